// Round 1
// baseline (237.190 us; speedup 1.0000x reference)
//
#include <hip/hip_runtime.h>

#define BLOCK 256
#define VEC 8
#define CHUNK (BLOCK * VEC)

__device__ __forceinline__ float bce_elem(float p, float t) {
    // matches jnp: -(t*clip(log p,-100) + (1-t)*clip(log1p(-p),-100))
    float lp  = fmaxf(__logf(p), -100.0f);     // v_log_f32(0) = -inf -> clamped to -100
    float l1p = fmaxf(log1pf(-p), -100.0f);
    return -(t * lp + (1.0f - t) * l1p);
}

__global__ __launch_bounds__(BLOCK) void seg_bce_kernel(
    const float* __restrict__ pred, const float* __restrict__ tgt,
    const int* __restrict__ batch, const int* __restrict__ mask,
    float* __restrict__ seg_bce, float* __restrict__ seg_cnt, int n)
{
    long base = (long)blockIdx.x * CHUNK + (long)threadIdx.x * VEC;
    int   cur  = -1;
    float accb = 0.0f, accc = 0.0f;

    if (base + VEC <= n) {
        const float4* p4 = reinterpret_cast<const float4*>(pred + base);
        const float4* t4 = reinterpret_cast<const float4*>(tgt + base);
        const int4*   b4 = reinterpret_cast<const int4*>(batch + base);
        const int4*   m4 = reinterpret_cast<const int4*>(mask + base);
        #pragma unroll
        for (int v = 0; v < VEC / 4; ++v) {
            float4 p = p4[v];
            float4 t = t4[v];
            int4   s = b4[v];
            int4   m = m4[v];
            float pv[4] = {p.x, p.y, p.z, p.w};
            float tv[4] = {t.x, t.y, t.z, t.w};
            int   sv[4] = {s.x, s.y, s.z, s.w};
            int   mv[4] = {m.x, m.y, m.z, m.w};
            #pragma unroll
            for (int j = 0; j < 4; ++j) {
                float mf = (float)mv[j];
                float b  = bce_elem(pv[j] * mf, tv[j]);
                if (sv[j] != cur) {                      // rare: segment boundary inside thread
                    if (cur >= 0) {
                        atomicAdd(&seg_bce[cur], accb);
                        atomicAdd(&seg_cnt[cur], accc);
                    }
                    cur = sv[j]; accb = 0.0f; accc = 0.0f;
                }
                accb += b;
                accc += mf;
            }
        }
    } else {
        for (int j = 0; j < VEC; ++j) {
            long idx = base + j;
            if (idx < n) {
                float mf = (float)mask[idx];
                float b  = bce_elem(pred[idx] * mf, tgt[idx]);
                int   s  = batch[idx];
                if (s != cur) {
                    if (cur >= 0) {
                        atomicAdd(&seg_bce[cur], accb);
                        atomicAdd(&seg_cnt[cur], accc);
                    }
                    cur = s; accb = 0.0f; accc = 0.0f;
                }
                accb += b;
                accc += mf;
            }
        }
    }

    // Wave-level combine of each lane's final run. batch is sorted, so a wave
    // is almost always segment-uniform -> one atomic pair per 64 lanes.
    int  first = __builtin_amdgcn_readfirstlane(cur);
    bool uni   = (bool)__all(cur == first);
    if (uni) {
        #pragma unroll
        for (int o = 32; o > 0; o >>= 1) {
            accb += __shfl_xor(accb, o);
            accc += __shfl_xor(accc, o);
        }
        if ((threadIdx.x & 63) == 0 && first >= 0) {
            atomicAdd(&seg_bce[first], accb);
            atomicAdd(&seg_cnt[first], accc);
        }
    } else if (cur >= 0) {
        atomicAdd(&seg_bce[cur], accb);
        atomicAdd(&seg_cnt[cur], accc);
    }
}

__global__ __launch_bounds__(256) void finalize_kernel(
    const float* __restrict__ seg_bce, const float* __restrict__ seg_cnt,
    const float* __restrict__ sat_pred, const float* __restrict__ sat_tgt,
    float* __restrict__ out, int Bseg)
{
    const float l1_over_b = (1.0f / 50.0f) / (float)Bseg;   // mean * L1
    float local = 0.0f;
    for (int i = threadIdx.x; i < Bseg; i += blockDim.x) {
        float c = seg_cnt[i];
        if (c > 0.0f) local += seg_bce[i] / fmaxf(c, 1.0f);
        local += bce_elem(sat_pred[i], sat_tgt[i]) * l1_over_b;
    }
    #pragma unroll
    for (int o = 32; o > 0; o >>= 1) local += __shfl_xor(local, o);
    __shared__ float ws[4];
    if ((threadIdx.x & 63) == 0) ws[threadIdx.x >> 6] = local;
    __syncthreads();
    if (threadIdx.x == 0) out[0] = ws[0] + ws[1] + ws[2] + ws[3];
}

extern "C" void kernel_launch(void* const* d_in, const int* in_sizes, int n_in,
                              void* d_out, int out_size, void* d_ws, size_t ws_size,
                              hipStream_t stream) {
    const float* y_mus_pred = (const float*)d_in[0];
    const float* y_mus      = (const float*)d_in[1];
    const float* y_sat_pred = (const float*)d_in[2];
    const float* y_sat      = (const float*)d_in[3];
    const int*   batch      = (const int*)d_in[4];
    const int*   mask       = (const int*)d_in[5];

    const int n    = in_sizes[0];
    const int Bseg = in_sizes[2];

    float* seg_bce = (float*)d_ws;
    float* seg_cnt = seg_bce + Bseg;

    // d_ws is re-poisoned (0xAA) before every launch -> zero the accumulators.
    hipMemsetAsync(d_ws, 0, 2 * (size_t)Bseg * sizeof(float), stream);

    const int nblocks = (n + CHUNK - 1) / CHUNK;
    seg_bce_kernel<<<nblocks, BLOCK, 0, stream>>>(
        y_mus_pred, y_mus, batch, mask, seg_bce, seg_cnt, n);
    finalize_kernel<<<1, 256, 0, stream>>>(
        seg_bce, seg_cnt, y_sat_pred, y_sat, (float*)d_out, Bseg);
}

// Round 2
// 224.457 us; speedup vs baseline: 1.0567x; 1.0567x over previous
//
#include <hip/hip_runtime.h>

#define BLOCK 256
#define VEC 8
#define CHUNK (BLOCK * VEC)

// Branch-free BCE matching jnp: -(t*clip(log p,-100) + (1-t)*clip(log1p(-p),-100))
// log1p(-p) -> __logf(1-p): max abs err ~6e-8 for p in [0,1), way inside threshold.
__device__ __forceinline__ float bce_elem(float p, float t) {
    float lp  = fmaxf(__logf(p), -100.0f);        // v_log_f32(0) = -inf -> clamped
    float l1p = fmaxf(__logf(1.0f - p), -100.0f);
    // -(t*lp + (1-t)*l1p) = -(t*(lp - l1p) + l1p)
    return -__builtin_fmaf(t, lp - l1p, l1p);
}

__global__ __launch_bounds__(BLOCK) void seg_bce_kernel(
    const float* __restrict__ pred, const float* __restrict__ tgt,
    const int* __restrict__ batch, const int* __restrict__ mask,
    float* __restrict__ seg_bce, float* __restrict__ seg_cnt, int n)
{
    long base = (long)blockIdx.x * CHUNK + (long)threadIdx.x * VEC;
    int   cur  = -1;
    float accb = 0.0f, accc = 0.0f;

    if (base + VEC <= n) {
        // Issue ALL loads up front (8 x 16B independent global_load_dwordx4).
        const float4* p4 = reinterpret_cast<const float4*>(pred + base);
        const float4* t4 = reinterpret_cast<const float4*>(tgt + base);
        const int4*   b4 = reinterpret_cast<const int4*>(batch + base);
        const int4*   m4 = reinterpret_cast<const int4*>(mask + base);
        float4 p0 = p4[0], p1 = p4[1];
        float4 t0 = t4[0], t1 = t4[1];
        int4   s0 = b4[0], s1 = b4[1];
        int4   m0 = m4[0], m1 = m4[1];

        if (s0.x == s1.w) {
            // FAST PATH (~99.8% of threads): whole range in one segment
            // (batch is sorted, so first==last implies all equal).
            float pv[8] = {p0.x, p0.y, p0.z, p0.w, p1.x, p1.y, p1.z, p1.w};
            float tv[8] = {t0.x, t0.y, t0.z, t0.w, t1.x, t1.y, t1.z, t1.w};
            int   mv[8] = {m0.x, m0.y, m0.z, m0.w, m1.x, m1.y, m1.z, m1.w};
            cur = s0.x;
            #pragma unroll
            for (int j = 0; j < 8; ++j) {
                float mf = (float)mv[j];
                accb += bce_elem(pv[j] * mf, tv[j]);
                accc += mf;
            }
        } else {
            // COLD PATH: segment boundary inside this thread's range.
            float pv[8] = {p0.x, p0.y, p0.z, p0.w, p1.x, p1.y, p1.z, p1.w};
            float tv[8] = {t0.x, t0.y, t0.z, t0.w, t1.x, t1.y, t1.z, t1.w};
            int   sv[8] = {s0.x, s0.y, s0.z, s0.w, s1.x, s1.y, s1.z, s1.w};
            int   mv[8] = {m0.x, m0.y, m0.z, m0.w, m1.x, m1.y, m1.z, m1.w};
            cur = sv[0];
            for (int j = 0; j < 8; ++j) {
                if (sv[j] != cur) {
                    atomicAdd(&seg_bce[cur], accb);
                    atomicAdd(&seg_cnt[cur], accc);
                    cur = sv[j]; accb = 0.0f; accc = 0.0f;
                }
                float mf = (float)mv[j];
                accb += bce_elem(pv[j] * mf, tv[j]);
                accc += mf;
            }
        }
    } else {
        // Tail block.
        for (int j = 0; j < VEC; ++j) {
            long idx = base + j;
            if (idx < n) {
                int s = batch[idx];
                if (s != cur) {
                    if (cur >= 0) {
                        atomicAdd(&seg_bce[cur], accb);
                        atomicAdd(&seg_cnt[cur], accc);
                    }
                    cur = s; accb = 0.0f; accc = 0.0f;
                }
                float mf = (float)mask[idx];
                accb += bce_elem(pred[idx] * mf, tgt[idx]);
                accc += mf;
            }
        }
    }

    // Wave-level combine: batch sorted -> wave almost always segment-uniform
    // -> one atomic pair per 64 lanes.
    int  first = __builtin_amdgcn_readfirstlane(cur);
    bool uni   = (bool)__all(cur == first);
    if (uni) {
        #pragma unroll
        for (int o = 32; o > 0; o >>= 1) {
            accb += __shfl_xor(accb, o);
            accc += __shfl_xor(accc, o);
        }
        if ((threadIdx.x & 63) == 0 && first >= 0) {
            atomicAdd(&seg_bce[first], accb);
            atomicAdd(&seg_cnt[first], accc);
        }
    } else if (cur >= 0) {
        atomicAdd(&seg_bce[cur], accb);
        atomicAdd(&seg_cnt[cur], accc);
    }
}

__global__ __launch_bounds__(256) void finalize_kernel(
    const float* __restrict__ seg_bce, const float* __restrict__ seg_cnt,
    const float* __restrict__ sat_pred, const float* __restrict__ sat_tgt,
    float* __restrict__ out, int Bseg)
{
    const float l1_over_b = (1.0f / 50.0f) / (float)Bseg;   // mean * L1
    float local = 0.0f;
    for (int i = threadIdx.x; i < Bseg; i += blockDim.x) {
        float c = seg_cnt[i];
        if (c > 0.0f) local += seg_bce[i] / fmaxf(c, 1.0f);
        local += bce_elem(sat_pred[i], sat_tgt[i]) * l1_over_b;
    }
    #pragma unroll
    for (int o = 32; o > 0; o >>= 1) local += __shfl_xor(local, o);
    __shared__ float ws[4];
    if ((threadIdx.x & 63) == 0) ws[threadIdx.x >> 6] = local;
    __syncthreads();
    if (threadIdx.x == 0) out[0] = ws[0] + ws[1] + ws[2] + ws[3];
}

extern "C" void kernel_launch(void* const* d_in, const int* in_sizes, int n_in,
                              void* d_out, int out_size, void* d_ws, size_t ws_size,
                              hipStream_t stream) {
    const float* y_mus_pred = (const float*)d_in[0];
    const float* y_mus      = (const float*)d_in[1];
    const float* y_sat_pred = (const float*)d_in[2];
    const float* y_sat      = (const float*)d_in[3];
    const int*   batch      = (const int*)d_in[4];
    const int*   mask       = (const int*)d_in[5];

    const int n    = in_sizes[0];
    const int Bseg = in_sizes[2];

    float* seg_bce = (float*)d_ws;
    float* seg_cnt = seg_bce + Bseg;

    // d_ws is re-poisoned (0xAA) before every launch -> zero the accumulators.
    hipMemsetAsync(d_ws, 0, 2 * (size_t)Bseg * sizeof(float), stream);

    const int nblocks = (n + CHUNK - 1) / CHUNK;
    seg_bce_kernel<<<nblocks, BLOCK, 0, stream>>>(
        y_mus_pred, y_mus, batch, mask, seg_bce, seg_cnt, n);
    finalize_kernel<<<1, 256, 0, stream>>>(
        seg_bce, seg_cnt, y_sat_pred, y_sat, (float*)d_out, Bseg);
}

// Round 3
// 163.271 us; speedup vs baseline: 1.4527x; 1.3747x over previous
//
#include <hip/hip_runtime.h>

#define BLOCK  256                 // threads per block (4 waves)
#define WAVES  (BLOCK / 64)
#define WELEM  512                 // elems per wave-region (64 lanes * 8)
#define BELEM  (WAVES * WELEM)     // 2048 elems per block per iteration
#define ITERS  4
#define SPAN   (BELEM * ITERS)     // 8192 contiguous elems per block

// Branch-free BCE matching jnp: -(t*clip(log p,-100) + (1-t)*clip(log1p(-p),-100))
// log1p(-p) -> __logf(1-p): abs err ~6e-8, far inside the 2e3 threshold.
__device__ __forceinline__ float bce_elem(float p, float t) {
    float lp  = fmaxf(__logf(p), -100.0f);        // v_log_f32(0) = -inf -> clamped
    float l1p = fmaxf(__logf(1.0f - p), -100.0f);
    return -__builtin_fmaf(t, lp - l1p, l1p);     // -(t*(lp-l1p) + l1p)
}

struct Regs {
    float4 p0, p1, t0, t1;
    int4   s0, s1, m0, m1;
};

__device__ __forceinline__ void load_regs(Regs& r,
    const float* __restrict__ pred, const float* __restrict__ tgt,
    const int* __restrict__ batch, const int* __restrict__ mask,
    long wb, int lane)
{
    // Region [wb, wb+512): load j covers elems wb + j*256 + lane*4 .. +3
    const float4* p4 = reinterpret_cast<const float4*>(pred + wb);
    const float4* t4 = reinterpret_cast<const float4*>(tgt + wb);
    const int4*   s4 = reinterpret_cast<const int4*>(batch + wb);
    const int4*   m4 = reinterpret_cast<const int4*>(mask + wb);
    r.p0 = p4[lane]; r.p1 = p4[64 + lane];
    r.t0 = t4[lane]; r.t1 = t4[64 + lane];
    r.s0 = s4[lane]; r.s1 = s4[64 + lane];
    r.m0 = m4[lane]; r.m1 = m4[64 + lane];
}

// Wave-collective: reduce (b,c) across 64 lanes, lane0 atomics into seg s.
__device__ __forceinline__ void wave_flush(int s, float b, float c,
    float* __restrict__ seg_bce, float* __restrict__ seg_cnt, int lane)
{
    #pragma unroll
    for (int o = 32; o > 0; o >>= 1) {
        b += __shfl_xor(b, o);
        c += __shfl_xor(c, o);
    }
    if (lane == 0 && s >= 0) {
        atomicAdd(&seg_bce[s], b);
        atomicAdd(&seg_cnt[s], c);
    }
}

__global__ __launch_bounds__(BLOCK) void seg_bce_kernel(
    const float* __restrict__ pred, const float* __restrict__ tgt,
    const int* __restrict__ batch, const int* __restrict__ mask,
    float* __restrict__ seg_bce, float* __restrict__ seg_cnt, int n)
{
    const int wave = threadIdx.x >> 6;
    const int lane = threadIdx.x & 63;
    const long blockBase = (long)blockIdx.x * SPAN;

    int   runSeg = -1;          // wave-uniform running segment
    float accb = 0.0f, accc = 0.0f;

    Regs r, rn;
    long wb0 = blockBase + (long)wave * WELEM;
    if (wb0 + WELEM <= n) load_regs(r, pred, tgt, batch, mask, wb0, lane);

    #pragma unroll
    for (int i = 0; i < ITERS; ++i) {
        long wb  = blockBase + (long)i * BELEM + (long)wave * WELEM;
        bool vec = (wb + WELEM <= n);

        // Prefetch next iteration's region before consuming this one.
        if (i + 1 < ITERS) {
            long wbn = wb + BELEM;
            if (wbn + WELEM <= n) load_regs(rn, pred, tgt, batch, mask, wbn, lane);
        }

        if (vec) {
            float pv[8] = {r.p0.x, r.p0.y, r.p0.z, r.p0.w, r.p1.x, r.p1.y, r.p1.z, r.p1.w};
            float tv[8] = {r.t0.x, r.t0.y, r.t0.z, r.t0.w, r.t1.x, r.t1.y, r.t1.z, r.t1.w};
            int   sv[8] = {r.s0.x, r.s0.y, r.s0.z, r.s0.w, r.s1.x, r.s1.y, r.s1.z, r.s1.w};
            int   mv[8] = {r.m0.x, r.m0.y, r.m0.z, r.m0.w, r.m1.x, r.m1.y, r.m1.z, r.m1.w};

            // batch sorted: region uniform iff first elem seg == last elem seg.
            int segFirst = __builtin_amdgcn_readfirstlane(r.s0.x);
            int segLast  = __builtin_amdgcn_readfirstlane(__shfl(r.s1.w, 63));

            if (segFirst == segLast) {
                // FAST PATH (~87% of regions): whole 512-elem region one segment.
                if (runSeg != segFirst) {
                    if (runSeg >= 0) wave_flush(runSeg, accb, accc, seg_bce, seg_cnt, lane);
                    accb = 0.0f; accc = 0.0f; runSeg = segFirst;
                }
                #pragma unroll
                for (int j = 0; j < 8; ++j) {
                    float mf = (float)mv[j];
                    accb += bce_elem(pv[j] * mf, tv[j]);
                    accc += mf;
                }
            } else {
                // BOUNDARY region: per-segment select + wave reduce (1-2 segs typ).
                if (runSeg >= 0) wave_flush(runSeg, accb, accc, seg_bce, seg_cnt, lane);
                accb = 0.0f; accc = 0.0f; runSeg = -1;
                float bv[8], cv[8];
                #pragma unroll
                for (int j = 0; j < 8; ++j) {
                    float mf = (float)mv[j];
                    bv[j] = bce_elem(pv[j] * mf, tv[j]);
                    cv[j] = mf;
                }
                for (int s = segFirst; s <= segLast; ++s) {
                    float pb = 0.0f, pc = 0.0f;
                    #pragma unroll
                    for (int j = 0; j < 8; ++j) {
                        if (sv[j] == s) { pb += bv[j]; pc += cv[j]; }
                    }
                    wave_flush(s, pb, pc, seg_bce, seg_cnt, lane);
                }
            }
        } else if (wb < n) {
            // Partial tail region (last block only): scalar per-lane path.
            if (runSeg >= 0) wave_flush(runSeg, accb, accc, seg_bce, seg_cnt, lane);
            accb = 0.0f; accc = 0.0f; runSeg = -1;
            int cur = -1; float ab = 0.0f, ac = 0.0f;
            #pragma unroll
            for (int g = 0; g < 2; ++g) {
                for (int e = 0; e < 4; ++e) {
                    long idx = wb + (long)g * 256 + (long)lane * 4 + e;
                    if (idx < n) {
                        int s = batch[idx];
                        if (s != cur) {
                            if (cur >= 0) {
                                atomicAdd(&seg_bce[cur], ab);
                                atomicAdd(&seg_cnt[cur], ac);
                            }
                            cur = s; ab = 0.0f; ac = 0.0f;
                        }
                        float mf = (float)mask[idx];
                        ab += bce_elem(pred[idx] * mf, tgt[idx]);
                        ac += mf;
                    }
                }
            }
            if (cur >= 0) {
                atomicAdd(&seg_bce[cur], ab);
                atomicAdd(&seg_cnt[cur], ac);
            }
        }
        r = rn;
    }

    if (runSeg >= 0) wave_flush(runSeg, accb, accc, seg_bce, seg_cnt, lane);
}

__global__ __launch_bounds__(256) void finalize_kernel(
    const float* __restrict__ seg_bce, const float* __restrict__ seg_cnt,
    const float* __restrict__ sat_pred, const float* __restrict__ sat_tgt,
    float* __restrict__ out, int Bseg)
{
    const float l1_over_b = (1.0f / 50.0f) / (float)Bseg;   // mean * L1
    float local = 0.0f;
    for (int i = threadIdx.x; i < Bseg; i += blockDim.x) {
        float c = seg_cnt[i];
        if (c > 0.0f) local += seg_bce[i] / fmaxf(c, 1.0f);
        local += bce_elem(sat_pred[i], sat_tgt[i]) * l1_over_b;
    }
    #pragma unroll
    for (int o = 32; o > 0; o >>= 1) local += __shfl_xor(local, o);
    __shared__ float ws[4];
    if ((threadIdx.x & 63) == 0) ws[threadIdx.x >> 6] = local;
    __syncthreads();
    if (threadIdx.x == 0) out[0] = ws[0] + ws[1] + ws[2] + ws[3];
}

extern "C" void kernel_launch(void* const* d_in, const int* in_sizes, int n_in,
                              void* d_out, int out_size, void* d_ws, size_t ws_size,
                              hipStream_t stream) {
    const float* y_mus_pred = (const float*)d_in[0];
    const float* y_mus      = (const float*)d_in[1];
    const float* y_sat_pred = (const float*)d_in[2];
    const float* y_sat      = (const float*)d_in[3];
    const int*   batch      = (const int*)d_in[4];
    const int*   mask       = (const int*)d_in[5];

    const int n    = in_sizes[0];
    const int Bseg = in_sizes[2];

    float* seg_bce = (float*)d_ws;
    float* seg_cnt = seg_bce + Bseg;

    // d_ws is re-poisoned (0xAA) before every launch -> zero the accumulators.
    hipMemsetAsync(d_ws, 0, 2 * (size_t)Bseg * sizeof(float), stream);

    const int nblocks = (n + SPAN - 1) / SPAN;
    seg_bce_kernel<<<nblocks, BLOCK, 0, stream>>>(
        y_mus_pred, y_mus, batch, mask, seg_bce, seg_cnt, n);
    finalize_kernel<<<1, 256, 0, stream>>>(
        seg_bce, seg_cnt, y_sat_pred, y_sat, (float*)d_out, Bseg);
}